// Round 3
// baseline (394.412 us; speedup 1.0000x reference)
//
#include <hip/hip_runtime.h>
#include <hip/hip_cooperative_groups.h>

namespace cg = cooperative_groups;

// Problem constants (B=2,S=4096,H=32,P=64,N=64,BLOCK=64)
#define B_ 2
#define S_ 4096
#define H_ 32
#define P_ 64
#define N_ 64
#define C_ 64
#define HP 2048   // H_*P_ : element stride per sequence step in X/Y
#define HN 2048   // H_*N_ : element stride per sequence step in Bm/Cm
#define NTILE 4096 // B_*C_*H_

typedef __attribute__((ext_vector_type(8))) short bf16x8;
typedef __attribute__((ext_vector_type(4))) float f32x4;

__device__ __forceinline__ float bf2f(unsigned int u16) {
    return __uint_as_float(u16 << 16);
}
__device__ __forceinline__ void unpack2(unsigned int u, float& lo, float& hi) {
    lo = __uint_as_float(u << 16);
    hi = __uint_as_float(u & 0xffff0000u);
}
__device__ __forceinline__ unsigned short f2bf(float f) {
    unsigned int u = __float_as_uint(f);
    u += 0x7fffu + ((u >> 16) & 1u);   // round-to-nearest-even
    return (unsigned short)(u >> 16);
}
// fp32 -> bf16 hi + bf16 lo (x ~= hi + lo, residual ~2^-18 * |x|)
__device__ __forceinline__ void split_bf(float x, unsigned short& h, unsigned short& l) {
    h = f2bf(x);
    l = f2bf(x - bf2f(h));
}

// Swizzled byte addresses inside a 64x64 ushort tile (row stride 128 B).
__device__ __forceinline__ int nsw(int r, int cb) {
    return (r << 7) + (cb ^ ((r & 7) << 4));
}
__device__ __forceinline__ int tsw(int r, int cb) {
    return (r << 7) + (cb ^ ((((r & 7) ^ (r >> 3)) & 7) << 4));
}

// ---------------------------------------------------------------------------
// Fused cooperative kernel.
//   P1: per-chunk states[p][n] (split-bf16 MFMA)          [tiles 0..4095]
//   P2: inter-chunk scan, in place, 4-deep prefetch       [units 0..511]
//   P3: Y = (masked-decay C·B^T)·X + exp(cs)·(C·S_enter)  [tiles 0..4095]
// LDS pool 49408 B -> 3 blocks/CU; grid = 3*256 co-resident (cooperative).
// ---------------------------------------------------------------------------
__global__ __launch_bounds__(256, 3) void fused(
    const void* __restrict__ Xg,
    const void* __restrict__ Ag,
    const void* __restrict__ Bg,
    const void* __restrict__ Cg,
    float* __restrict__ states,
    float* __restrict__ sums,
    void* __restrict__ Yg)
{
    __shared__ __align__(16) unsigned char pool[49408];
    char*  p0  = (char*)pool;
    float* fsh = (float*)(pool + 49152);   // 64 floats: wdec / dexp / csh

    const int tid  = threadIdx.x;
    const int nblk = gridDim.x;
    cg::grid_group grid = cg::this_grid();

    // ------ dtype self-detect (uniform across blocks/waves; replaces k0) ----
    // A is strictly negative. bf16 data: sampled ushorts all have sign bit.
    // fp32 data: even-index ushorts are mantissa-low halves, ~50% positive.
    int isf32;
    {
        unsigned short du = ((const unsigned short*)Ag)[(tid & 63) * 2];
        unsigned long long m = __ballot(((du & 0x8000u) == 0) ? 1 : 0);
        isf32 = (__popcll(m) > 8) ? 1 : 0;
    }

    const int l  = tid & 63, w4 = tid >> 6;
    const int lr = l & 15,  q  = l >> 4;

    // ======================= Phase 1: chunk states ==========================
    for (int tile = blockIdx.x; tile < NTILE; tile += nblk) {
        const int h = tile & 31, c = (tile >> 5) & 63, b = tile >> 11;
        char* XThb = p0;            // X^T [p][t] hi, tsw
        char* XTlb = p0 + 8192;
        char* BThb = p0 + 16384;    // Bw^T [n][t] hi, tsw
        char* BTlb = p0 + 24576;
        float* wdec = fsh;

        const size_t baseX = (size_t)((b * S_ + c * 64) * H_ + h) * P_;
        const size_t baseB = (size_t)((b * S_ + c * 64) * H_ + h) * N_;

        // issue X/B global loads first: latency hides under the A chain
        uint4 xA[2], xB[2], bA[2], bB[2];
        #pragma unroll
        for (int it = 0; it < 2; ++it) {
            int t = (tid >> 3) + it * 32;
            int e = (tid & 7) * 8;
            if (isf32) {
                const float* Xp = (const float*)Xg + baseX + (size_t)t * HP + e;
                const float* Bp = (const float*)Bg + baseB + (size_t)t * HN + e;
                xA[it] = *(const uint4*)Xp;
                xB[it] = *(const uint4*)(Xp + 4);
                bA[it] = *(const uint4*)Bp;
                bB[it] = *(const uint4*)(Bp + 4);
            } else {
                const unsigned short* Xp = (const unsigned short*)Xg + baseX + (size_t)t * HP + e;
                const unsigned short* Bp = (const unsigned short*)Bg + baseB + (size_t)t * HN + e;
                xA[it] = *(const uint4*)Xp;
                bA[it] = *(const uint4*)Bp;
            }
        }

        // A cumsum over the chunk (wave 0), decay weights, chunk sum
        if (tid < 64) {
            int ai = (b * S_ + c * 64 + tid) * H_ + h;
            float a = isf32 ? ((const float*)Ag)[ai] : bf2f(((const unsigned short*)Ag)[ai]);
            float x = a;
            #pragma unroll
            for (int off = 1; off < 64; off <<= 1) {
                float y = __shfl_up(x, off, 64);
                if (tid >= off) x += y;
            }
            float tot = __shfl(x, 63, 64);
            wdec[tid] = __expf(tot - x);
            if (tid == 63) sums[(b * H_ + h) * C_ + c] = tot;
        }
        __syncthreads();

        // split + scatter from registers
        #pragma unroll
        for (int it = 0; it < 2; ++it) {
            int t = (tid >> 3) + it * 32;
            int e = (tid & 7) * 8;
            float xv[8], bv[8];
            if (isf32) {
                xv[0]=__uint_as_float(xA[it].x); xv[1]=__uint_as_float(xA[it].y);
                xv[2]=__uint_as_float(xA[it].z); xv[3]=__uint_as_float(xA[it].w);
                xv[4]=__uint_as_float(xB[it].x); xv[5]=__uint_as_float(xB[it].y);
                xv[6]=__uint_as_float(xB[it].z); xv[7]=__uint_as_float(xB[it].w);
                bv[0]=__uint_as_float(bA[it].x); bv[1]=__uint_as_float(bA[it].y);
                bv[2]=__uint_as_float(bA[it].z); bv[3]=__uint_as_float(bA[it].w);
                bv[4]=__uint_as_float(bB[it].x); bv[5]=__uint_as_float(bB[it].y);
                bv[6]=__uint_as_float(bB[it].z); bv[7]=__uint_as_float(bB[it].w);
            } else {
                unpack2(xA[it].x, xv[0], xv[1]); unpack2(xA[it].y, xv[2], xv[3]);
                unpack2(xA[it].z, xv[4], xv[5]); unpack2(xA[it].w, xv[6], xv[7]);
                unpack2(bA[it].x, bv[0], bv[1]); unpack2(bA[it].y, bv[2], bv[3]);
                unpack2(bA[it].z, bv[4], bv[5]); unpack2(bA[it].w, bv[6], bv[7]);
            }
            float w = wdec[t];
            #pragma unroll
            for (int i = 0; i < 8; ++i) {
                int o = tsw(e + i, 2 * t);
                unsigned short hh, ll;
                split_bf(xv[i], hh, ll);
                *(unsigned short*)(XThb + o) = hh;
                *(unsigned short*)(XTlb + o) = ll;
                split_bf(bv[i] * w, hh, ll);
                *(unsigned short*)(BThb + o) = hh;
                *(unsigned short*)(BTlb + o) = ll;
            }
        }
        __syncthreads();

        const int rowA = 16 * w4 + lr;
        const int oa0 = tsw(rowA, 16 * q);
        const int oa1 = tsw(rowA, 16 * q + 64);
        bf16x8 a0h = *(const bf16x8*)(XThb + oa0);
        bf16x8 a1h = *(const bf16x8*)(XThb + oa1);
        bf16x8 a0l = *(const bf16x8*)(XTlb + oa0);
        bf16x8 a1l = *(const bf16x8*)(XTlb + oa1);

        f32x4 acc[4];
        #pragma unroll
        for (int nt = 0; nt < 4; ++nt) acc[nt] = (f32x4){0.f, 0.f, 0.f, 0.f};
        #pragma unroll
        for (int nt = 0; nt < 4; ++nt) {
            int ob0 = tsw(16 * nt + lr, 16 * q);
            int ob1 = tsw(16 * nt + lr, 16 * q + 64);
            bf16x8 b0h = *(const bf16x8*)(BThb + ob0);
            bf16x8 b0l = *(const bf16x8*)(BTlb + ob0);
            bf16x8 b1h = *(const bf16x8*)(BThb + ob1);
            bf16x8 b1l = *(const bf16x8*)(BTlb + ob1);
            acc[nt] = __builtin_amdgcn_mfma_f32_16x16x32_bf16(a0h, b0h, acc[nt], 0, 0, 0);
            acc[nt] = __builtin_amdgcn_mfma_f32_16x16x32_bf16(a1h, b1h, acc[nt], 0, 0, 0);
            acc[nt] = __builtin_amdgcn_mfma_f32_16x16x32_bf16(a0h, b0l, acc[nt], 0, 0, 0);
            acc[nt] = __builtin_amdgcn_mfma_f32_16x16x32_bf16(a1h, b1l, acc[nt], 0, 0, 0);
            acc[nt] = __builtin_amdgcn_mfma_f32_16x16x32_bf16(a0l, b0h, acc[nt], 0, 0, 0);
            acc[nt] = __builtin_amdgcn_mfma_f32_16x16x32_bf16(a1l, b1h, acc[nt], 0, 0, 0);
        }

        float* sp = states + (size_t)((b * C_ + c) * H_ + h) * 4096;
        #pragma unroll
        for (int nt = 0; nt < 4; ++nt)
            #pragma unroll
            for (int r = 0; r < 4; ++r) {
                int p = 16 * w4 + 4 * q + r;
                int n = 16 * nt + lr;
                sp[p * 64 + n] = acc[nt][r];
            }
        __syncthreads();   // protect LDS reuse across tiles
    }

    grid.sync();

    // ======================= Phase 2: inter-chunk scan ======================
    for (int u = blockIdx.x; u < 512; u += nblk) {
        const int split = u & 7;
        const int bh = u >> 3;
        const int h = bh & 31;
        const int b = bh >> 5;
        __syncthreads();
        if (tid < 64) fsh[tid] = __expf(sums[(b * H_ + h) * C_ + tid]);
        __syncthreads();
        const int e = split * 512 + tid * 2;
        float* p = states + ((size_t)(b * C_) * H_ + h) * 4096 + e;
        const size_t cstr = (size_t)H_ * 4096;
        float2 S = make_float2(0.f, 0.f);
        float2 buf[4];   // 4-deep prefetch ring (statically indexed via unroll)
        #pragma unroll
        for (int d = 0; d < 4; ++d) buf[d] = *(const float2*)(p + d * cstr);
        #pragma unroll 4
        for (int cc = 0; cc < 64; ++cc) {
            float2 st = buf[cc & 3];
            if (cc + 4 < 64) buf[cc & 3] = *(const float2*)(p + (size_t)(cc + 4) * cstr);
            float dg = fsh[cc];
            *(float2*)(p + (size_t)cc * cstr) = S;   // S_enter[cc]
            S.x = S.x * dg + st.x;
            S.y = S.y * dg + st.y;
        }
    }

    grid.sync();

    // ======================= Phase 3: Y =====================================
    for (int tile = blockIdx.x; tile < NTILE; tile += nblk) {
        const int h = tile & 31, c = (tile >> 5) & 63, b = tile >> 11;
        char* Chb = p0;             // C [t][n] hi, nsw
        char* Clb = p0 + 8192;
        char* Bhb = p0 + 16384;     // B [s][n] hi, nsw; reused as M [t][s]
        char* Blb = p0 + 24576;
        char* Shb = p0 + 32768;     // S_enter [p][n] hi, nsw; reused as X^T [p][s] tsw
        char* Slb = p0 + 40960;
        float* csh = fsh;

        if (tid < 64) {
            int ai = (b * S_ + c * 64 + tid) * H_ + h;
            float a = isf32 ? ((const float*)Ag)[ai] : bf2f(((const unsigned short*)Ag)[ai]);
            float x = a;
            #pragma unroll
            for (int off = 1; off < 64; off <<= 1) {
                float y = __shfl_up(x, off, 64);
                if (tid >= off) x += y;
            }
            csh[tid] = x;
        }

        const size_t baseX = (size_t)((b * S_ + c * 64) * H_ + h) * P_;
        const size_t baseN = (size_t)((b * S_ + c * 64) * H_ + h) * N_;

        // preload X into registers (consumed after barrier2)
        uint4 xq0[2], xq1[2];
        #pragma unroll
        for (int it = 0; it < 2; ++it) {
            int t = (tid >> 3) + it * 32;
            int e = (tid & 7) * 8;
            if (isf32) {
                const float* Xp = (const float*)Xg + baseX + (size_t)t * HP + e;
                xq0[it] = *(const uint4*)Xp;
                xq1[it] = *(const uint4*)(Xp + 4);
            } else {
                const unsigned short* Xp = (const unsigned short*)Xg + baseX + (size_t)t * HP + e;
                xq0[it] = *(const uint4*)Xp;
            }
        }

        // stage C and B (natural hi/lo)
        #pragma unroll
        for (int it = 0; it < 2; ++it) {
            int t = (tid >> 3) + it * 32;
            int e = (tid & 7) * 8;
            float cv[8], bv[8];
            if (isf32) {
                const float* Cp = (const float*)Cg + baseN + (size_t)t * HN + e;
                const float* Bp = (const float*)Bg + baseN + (size_t)t * HN + e;
                float4 c0 = *(const float4*)Cp;
                float4 c1 = *(const float4*)(Cp + 4);
                float4 b0 = *(const float4*)Bp;
                float4 b1 = *(const float4*)(Bp + 4);
                cv[0]=c0.x; cv[1]=c0.y; cv[2]=c0.z; cv[3]=c0.w;
                cv[4]=c1.x; cv[5]=c1.y; cv[6]=c1.z; cv[7]=c1.w;
                bv[0]=b0.x; bv[1]=b0.y; bv[2]=b0.z; bv[3]=b0.w;
                bv[4]=b1.x; bv[5]=b1.y; bv[6]=b1.z; bv[7]=b1.w;
            } else {
                const unsigned short* Cp = (const unsigned short*)Cg + baseN + (size_t)t * HN + e;
                const unsigned short* Bp = (const unsigned short*)Bg + baseN + (size_t)t * HN + e;
                uint4 rc = *(const uint4*)Cp;
                uint4 rb = *(const uint4*)Bp;
                unpack2(rc.x, cv[0], cv[1]); unpack2(rc.y, cv[2], cv[3]);
                unpack2(rc.z, cv[4], cv[5]); unpack2(rc.w, cv[6], cv[7]);
                unpack2(rb.x, bv[0], bv[1]); unpack2(rb.y, bv[2], bv[3]);
                unpack2(rb.z, bv[4], bv[5]); unpack2(rb.w, bv[6], bv[7]);
            }
            int o = nsw(t, 2 * e);
            unsigned short hs[8], ls[8];
            #pragma unroll
            for (int i = 0; i < 8; ++i) split_bf(cv[i], hs[i], ls[i]);
            {
                uint4 uh, ul;
                uh.x = (unsigned int)hs[0] | ((unsigned int)hs[1] << 16);
                uh.y = (unsigned int)hs[2] | ((unsigned int)hs[3] << 16);
                uh.z = (unsigned int)hs[4] | ((unsigned int)hs[5] << 16);
                uh.w = (unsigned int)hs[6] | ((unsigned int)hs[7] << 16);
                ul.x = (unsigned int)ls[0] | ((unsigned int)ls[1] << 16);
                ul.y = (unsigned int)ls[2] | ((unsigned int)ls[3] << 16);
                ul.z = (unsigned int)ls[4] | ((unsigned int)ls[5] << 16);
                ul.w = (unsigned int)ls[6] | ((unsigned int)ls[7] << 16);
                *(uint4*)(Chb + o) = uh;
                *(uint4*)(Clb + o) = ul;
            }
            #pragma unroll
            for (int i = 0; i < 8; ++i) split_bf(bv[i], hs[i], ls[i]);
            {
                uint4 uh, ul;
                uh.x = (unsigned int)hs[0] | ((unsigned int)hs[1] << 16);
                uh.y = (unsigned int)hs[2] | ((unsigned int)hs[3] << 16);
                uh.z = (unsigned int)hs[4] | ((unsigned int)hs[5] << 16);
                uh.w = (unsigned int)hs[6] | ((unsigned int)hs[7] << 16);
                ul.x = (unsigned int)ls[0] | ((unsigned int)ls[1] << 16);
                ul.y = (unsigned int)ls[2] | ((unsigned int)ls[3] << 16);
                ul.z = (unsigned int)ls[4] | ((unsigned int)ls[5] << 16);
                ul.w = (unsigned int)ls[6] | ((unsigned int)ls[7] << 16);
                *(uint4*)(Bhb + o) = uh;
                *(uint4*)(Blb + o) = ul;
            }
        }

        // stage S_enter [p][n] (fp32 workspace) as hi/lo
        {
            const float* sb = states + (size_t)((b * C_ + c) * H_ + h) * 4096;
            #pragma unroll
            for (int k = 0; k < 4; ++k) {
                int e2 = (k * 256 + tid) * 4;
                float4 v = *(const float4*)(sb + e2);
                unsigned short h0,l0,h1,l1,h2,l2,h3,l3;
                split_bf(v.x, h0, l0); split_bf(v.y, h1, l1);
                split_bf(v.z, h2, l2); split_bf(v.w, h3, l3);
                uint2 uh, ul;
                uh.x = (unsigned int)h0 | ((unsigned int)h1 << 16);
                uh.y = (unsigned int)h2 | ((unsigned int)h3 << 16);
                ul.x = (unsigned int)l0 | ((unsigned int)l1 << 16);
                ul.y = (unsigned int)l2 | ((unsigned int)l3 << 16);
                int o = nsw(e2 >> 6, 2 * (e2 & 63));
                *(uint2*)(Shb + o) = uh;
                *(uint2*)(Slb + o) = ul;
            }
        }
        __syncthreads();

        const int tA = 16 * w4 + lr;
        const int oa0 = nsw(tA, 16 * q);
        const int oa1 = nsw(tA, 16 * q + 64);
        bf16x8 ac0h = *(const bf16x8*)(Chb + oa0);
        bf16x8 ac1h = *(const bf16x8*)(Chb + oa1);
        bf16x8 ac0l = *(const bf16x8*)(Clb + oa0);
        bf16x8 ac1l = *(const bf16x8*)(Clb + oa1);

        // MFMA#1: M = C·B^T
        f32x4 mac[4];
        #pragma unroll
        for (int st = 0; st < 4; ++st) mac[st] = (f32x4){0.f, 0.f, 0.f, 0.f};
        #pragma unroll
        for (int st = 0; st < 4; ++st) {
            int ob0 = nsw(16 * st + lr, 16 * q);
            int ob1 = nsw(16 * st + lr, 16 * q + 64);
            bf16x8 b0h = *(const bf16x8*)(Bhb + ob0);
            bf16x8 b0l = *(const bf16x8*)(Blb + ob0);
            bf16x8 b1h = *(const bf16x8*)(Bhb + ob1);
            bf16x8 b1l = *(const bf16x8*)(Blb + ob1);
            mac[st] = __builtin_amdgcn_mfma_f32_16x16x32_bf16(ac0h, b0h, mac[st], 0, 0, 0);
            mac[st] = __builtin_amdgcn_mfma_f32_16x16x32_bf16(ac1h, b1h, mac[st], 0, 0, 0);
            mac[st] = __builtin_amdgcn_mfma_f32_16x16x32_bf16(ac0h, b0l, mac[st], 0, 0, 0);
            mac[st] = __builtin_amdgcn_mfma_f32_16x16x32_bf16(ac1h, b1l, mac[st], 0, 0, 0);
            mac[st] = __builtin_amdgcn_mfma_f32_16x16x32_bf16(ac0l, b0h, mac[st], 0, 0, 0);
            mac[st] = __builtin_amdgcn_mfma_f32_16x16x32_bf16(ac1l, b1h, mac[st], 0, 0, 0);
        }

        // MFMA#3: Yoff = C·S
        f32x4 yacO[4];
        #pragma unroll
        for (int pt = 0; pt < 4; ++pt) yacO[pt] = (f32x4){0.f, 0.f, 0.f, 0.f};
        #pragma unroll
        for (int pt = 0; pt < 4; ++pt) {
            int os0 = nsw(16 * pt + lr, 16 * q);
            int os1 = nsw(16 * pt + lr, 16 * q + 64);
            bf16x8 s0h = *(const bf16x8*)(Shb + os0);
            bf16x8 s0l = *(const bf16x8*)(Slb + os0);
            bf16x8 s1h = *(const bf16x8*)(Shb + os1);
            bf16x8 s1l = *(const bf16x8*)(Slb + os1);
            yacO[pt] = __builtin_amdgcn_mfma_f32_16x16x32_bf16(ac0h, s0h, yacO[pt], 0, 0, 0);
            yacO[pt] = __builtin_amdgcn_mfma_f32_16x16x32_bf16(ac1h, s1h, yacO[pt], 0, 0, 0);
            yacO[pt] = __builtin_amdgcn_mfma_f32_16x16x32_bf16(ac0h, s0l, yacO[pt], 0, 0, 0);
            yacO[pt] = __builtin_amdgcn_mfma_f32_16x16x32_bf16(ac1h, s1l, yacO[pt], 0, 0, 0);
            yacO[pt] = __builtin_amdgcn_mfma_f32_16x16x32_bf16(ac0l, s0h, yacO[pt], 0, 0, 0);
            yacO[pt] = __builtin_amdgcn_mfma_f32_16x16x32_bf16(ac1l, s1h, yacO[pt], 0, 0, 0);
        }
        __syncthreads();   // all waves done reading B and S regions

        // write M (mask + segment decay, fp32 -> hi/lo) over B region
        float ct[4];
        #pragma unroll
        for (int r = 0; r < 4; ++r) ct[r] = csh[16 * w4 + 4 * q + r];
        #pragma unroll
        for (int st = 0; st < 4; ++st) {
            int s = 16 * st + lr;
            float cs_s = csh[s];
            #pragma unroll
            for (int r = 0; r < 4; ++r) {
                int t = 16 * w4 + 4 * q + r;
                float v = (s <= t) ? mac[st][r] * __expf(ct[r] - cs_s) : 0.f;
                unsigned short hh, ll;
                split_bf(v, hh, ll);
                int o = nsw(t, 2 * s);
                *(unsigned short*)(Bhb + o) = hh;
                *(unsigned short*)(Blb + o) = ll;
            }
        }

        // scatter X^T [p][s] hi/lo over S region (from preloaded registers)
        #pragma unroll
        for (int it = 0; it < 2; ++it) {
            int t = (tid >> 3) + it * 32;
            int e = (tid & 7) * 8;
            float xv[8];
            if (isf32) {
                xv[0] = __uint_as_float(xq0[it].x); xv[1] = __uint_as_float(xq0[it].y);
                xv[2] = __uint_as_float(xq0[it].z); xv[3] = __uint_as_float(xq0[it].w);
                xv[4] = __uint_as_float(xq1[it].x); xv[5] = __uint_as_float(xq1[it].y);
                xv[6] = __uint_as_float(xq1[it].z); xv[7] = __uint_as_float(xq1[it].w);
            } else {
                unpack2(xq0[it].x, xv[0], xv[1]); unpack2(xq0[it].y, xv[2], xv[3]);
                unpack2(xq0[it].z, xv[4], xv[5]); unpack2(xq0[it].w, xv[6], xv[7]);
            }
            #pragma unroll
            for (int i = 0; i < 8; ++i) {
                unsigned short hh, ll;
                split_bf(xv[i], hh, ll);
                int o = tsw(e + i, 2 * t);
                *(unsigned short*)(Shb + o) = hh;
                *(unsigned short*)(Slb + o) = ll;
            }
        }
        __syncthreads();

        // MFMA#2: Ydiag = M·X
        const int om0 = nsw(tA, 16 * q);
        const int om1 = nsw(tA, 16 * q + 64);
        bf16x8 am0h = *(const bf16x8*)(Bhb + om0);
        bf16x8 am1h = *(const bf16x8*)(Bhb + om1);
        bf16x8 am0l = *(const bf16x8*)(Blb + om0);
        bf16x8 am1l = *(const bf16x8*)(Blb + om1);
        f32x4 yacD[4];
        #pragma unroll
        for (int pt = 0; pt < 4; ++pt) yacD[pt] = (f32x4){0.f, 0.f, 0.f, 0.f};
        #pragma unroll
        for (int pt = 0; pt < 4; ++pt) {
            int ox0 = tsw(16 * pt + lr, 16 * q);
            int ox1 = tsw(16 * pt + lr, 16 * q + 64);
            bf16x8 x0h = *(const bf16x8*)(Shb + ox0);
            bf16x8 x0l = *(const bf16x8*)(Slb + ox0);
            bf16x8 x1h = *(const bf16x8*)(Shb + ox1);
            bf16x8 x1l = *(const bf16x8*)(Slb + ox1);
            yacD[pt] = __builtin_amdgcn_mfma_f32_16x16x32_bf16(am0h, x0h, yacD[pt], 0, 0, 0);
            yacD[pt] = __builtin_amdgcn_mfma_f32_16x16x32_bf16(am1h, x1h, yacD[pt], 0, 0, 0);
            yacD[pt] = __builtin_amdgcn_mfma_f32_16x16x32_bf16(am0h, x0l, yacD[pt], 0, 0, 0);
            yacD[pt] = __builtin_amdgcn_mfma_f32_16x16x32_bf16(am1h, x1l, yacD[pt], 0, 0, 0);
            yacD[pt] = __builtin_amdgcn_mfma_f32_16x16x32_bf16(am0l, x0h, yacD[pt], 0, 0, 0);
            yacD[pt] = __builtin_amdgcn_mfma_f32_16x16x32_bf16(am1l, x1h, yacD[pt], 0, 0, 0);
        }

        // epilogue: Y[t][p] = Ydiag + exp(cs[t]) * Yoff
        float ge[4];
        #pragma unroll
        for (int r = 0; r < 4; ++r) ge[r] = __expf(ct[r]);
        if (!isf32) {
            unsigned short* Yp = (unsigned short*)Yg + baseX;
            #pragma unroll
            for (int pt = 0; pt < 4; ++pt)
                #pragma unroll
                for (int r = 0; r < 4; ++r) {
                    int t = 16 * w4 + 4 * q + r;
                    Yp[(size_t)t * HP + 16 * pt + lr] = f2bf(yacD[pt][r] + ge[r] * yacO[pt][r]);
                }
        } else {
            float* Yp = (float*)Yg + baseX;
            #pragma unroll
            for (int pt = 0; pt < 4; ++pt)
                #pragma unroll
                for (int r = 0; r < 4; ++r) {
                    int t = 16 * w4 + 4 * q + r;
                    Yp[(size_t)t * HP + 16 * pt + lr] = yacD[pt][r] + ge[r] * yacO[pt][r];
                }
        }
        __syncthreads();   // protect LDS reuse across tiles
    }
}

extern "C" void kernel_launch(void* const* d_in, const int* in_sizes, int n_in,
                              void* d_out, int out_size, void* d_ws, size_t ws_size,
                              hipStream_t stream) {
    void* X  = d_in[0];
    void* A  = d_in[1];
    void* Bm = d_in[2];
    void* Cm = d_in[3];

    // ws layout: [0..15] flag int (16B, unused now), sums (4096 f), states (16M f)
    float* sums   = (float*)d_ws + 16;
    float* states = (float*)d_ws + 16 + 4096;
    void*  Y      = d_out;

    // cooperative grid: exactly the co-resident capacity (queried once)
    static int grid_blocks = 0;
    if (grid_blocks == 0) {
        int nb = 0;
        hipError_t e = hipOccupancyMaxActiveBlocksPerMultiprocessor(&nb, fused, 256, 0);
        if (e != hipSuccess || nb < 1) nb = 1;
        if (nb > 3) nb = 3;
        grid_blocks = nb * 256;
    }

    void* args[] = { &X, &A, &Bm, &Cm, (void*)&states, (void*)&sums, &Y };
    hipLaunchCooperativeKernel((const void*)fused, dim3(grid_blocks), dim3(256),
                               args, 0, stream);
}